// Round 19
// baseline (56.967 us; speedup 1.0000x reference)
//
#include <hip/hip_runtime.h>
#include <hip/hip_fp16.h>
#include <math.h>

#define FL     8192
#define BS     4096      // block step = FL/2
#define CD     16
#define BATCH  32
#define SEQ    262144
#define NPAIR  32        // 64 blocks -> 32 pairs
#define BSTR   36        // LDS block stride (32 elems + 4 pad) -> 144B, 16B-aligned
#define LDSN   (256*BSTR) // 9216 half2 = 36 KiB

// Packed fp32 complex: <2 x float> -> v_pk_add_f32 / v_pk_fma_f32 on gfx950.
typedef float vf2 __attribute__((ext_vector_type(2)));
__device__ __forceinline__ vf2 mkv(float x, float y){ vf2 v; v.x = x; v.y = y; return v; }
__device__ __forceinline__ vf2 cmul(vf2 a, vf2 b){            // a * b
    const vf2 c = mkv(-a.y, a.x) * mkv(b.y, b.y);
    return a * mkv(b.x, b.x) + c;
}
__device__ __forceinline__ vf2 mri(vf2 a, float c, float s){  // a * (c + i s)
    const vf2 t = mkv(-a.y, a.x) * mkv(s, s);
    return a * mkv(c, c) + t;
}

// fp16 LDS staging (addresses are PRE-PADDED by caller)
__device__ __forceinline__ void sth(__half2* buf, int i, vf2 v){ buf[i] = __floats2half2_rn(v.x, v.y); }
__device__ __forceinline__ vf2 ldh(const __half2* buf, int i){ const float2 f = __half22float2(buf[i]); return mkv(f.x, f.y); }
// uint <-> fp16x2 for vectorized (b128) LDS access in pass E
__device__ __forceinline__ vf2 h2f(unsigned u){ const float2 f = __half22float2(__builtin_bit_cast(__half2, u)); return mkv(f.x, f.y); }
__device__ __forceinline__ unsigned f2h(vf2 v){ return __builtin_bit_cast(unsigned, __floats2half2_rn(v.x, v.y)); }

// flat position p <-> natural bin k maps for passes A(R16,s512),B(R16,s32),E(32-block)
// p = 512*qA + 32*qB + w  <->  k = qA + 16*qB + 256*w   (logical, unpadded)
__device__ __forceinline__ int pos_of_bin(int k){
    return ((k&15)<<9) | (((k>>4)&15)<<5) | (k>>8);
}

// ---------------------------------------------------------------------------
// In-register 16-point DFT over d[S*0..S*15], 4x4 Cooley-Tukey.
// INV: conjugate (inverse, unnormalized). HALF: inputs d[S*8..S*15] are zero.
// ---------------------------------------------------------------------------
template<bool INV, bool HALF, int S>
__device__ __forceinline__ void dft16(vf2* d){
    constexpr float sgn = INV ? 1.f : -1.f;          // e^{sgn*i*2pi*k/16}
    constexpr float C1 = 0.923879532511287f;          // cos(pi/8)
    constexpr float S1 = 0.382683432365090f;          // sin(pi/8)
    constexpr float R  = 0.707106781186548f;
    vf2 u[16];
#pragma unroll
    for (int b=0;b<4;++b){
        const vf2 a0=d[S*b], a1=d[S*(4+b)];
        if (HALF){
            const vf2 ja1 = mkv(-sgn*a1.y, sgn*a1.x);
            u[4*b+0]=a0+a1;
            u[4*b+1]=a0+ja1;
            u[4*b+2]=a0-a1;
            u[4*b+3]=a0-ja1;
        } else {
            const vf2 a2=d[S*(8+b)], a3=d[S*(12+b)];
            const vf2 s0=a0+a2, s1=a0-a2;
            const vf2 s2=a1+a3, s3=a1-a3;
            const vf2 js3 = mkv(-sgn*s3.y, sgn*s3.x);
            u[4*b+0]=s0+s2;
            u[4*b+1]=s1+js3;
            u[4*b+2]=s0-s2;
            u[4*b+3]=s1-js3;
        }
    }
    u[4+1] = mri(u[4+1],  C1, sgn*S1);
    u[4+2] = mri(u[4+2],  R,  sgn*R );
    u[4+3] = mri(u[4+3],  S1, sgn*C1);
    u[8+1] = mri(u[8+1],  R,  sgn*R );
    u[8+2] = mri(u[8+2],  0.f, sgn);
    u[8+3] = mri(u[8+3], -R,  sgn*R );
    u[12+1]= mri(u[12+1], S1, sgn*C1);
    u[12+2]= mri(u[12+2],-R,  sgn*R );
    u[12+3]= mri(u[12+3],-C1,-sgn*S1);
#pragma unroll
    for (int c=0;c<4;++c){
        const vf2 a0=u[c], a1=u[4+c], a2=u[8+c], a3=u[12+c];
        const vf2 s0=a0+a2, s1=a0-a2;
        const vf2 s2=a1+a3, s3=a1-a3;
        const vf2 js3 = mkv(-sgn*s3.y, sgn*s3.x);
        d[S*(c+0)] =s0+s2;
        d[S*(c+4)] =s1+js3;
        d[S*(c+8)] =s0-s2;
        d[S*(c+12)]=s1-js3;
    }
}

// log-depth twiddle: w[q] = w1^q via pairwise products (depth 4), d[q] *= w[q].
__device__ __forceinline__ void tw_apply(vf2* d, vf2 w1){
    vf2 w[16];
    w[1] = w1;
#pragma unroll
    for (int q=2;q<16;++q) w[q] = cmul(w[q>>1], w[q-(q>>1)]);
#pragma unroll
    for (int q=1;q<16;++q) d[q] = cmul(d[q], w[q]);
}
// same powers applied to d[q] and d[16+q] (shared-twiddle butterfly pair)
__device__ __forceinline__ void tw_apply2(vf2* d, vf2 w1){
    vf2 w[16];
    w[1] = w1;
#pragma unroll
    for (int q=2;q<16;++q) w[q] = cmul(w[q>>1], w[q-(q>>1)]);
#pragma unroll
    for (int q=1;q<16;++q){ d[q] = cmul(d[q], w[q]); d[16+q] = cmul(d[16+q], w[q]); }
}

// ---------------------------------------------------------------------------
// Heff pair-based + fused zeroing of EVEN output spans only (odd spans are
// sole-writer plain-stores in fft_kernel and need no zeroing).
// ---------------------------------------------------------------------------
__global__ void h_kernel(const float* __restrict__ c,  const float* __restrict__ Wf,
                         const float* __restrict__ bfv, const float* __restrict__ Wp,
                         const float* __restrict__ bpv, float2* __restrict__ H,
                         float4* __restrict__ outz){
    const int f = blockIdx.x*256 + threadIdx.x;   // 0..4095
    const int b = blockIdx.y;
    const int g = (FL - f) & (FL - 1);

    // ---- zero even spans: 131072 thr x 8 float4 = 16.7 MB (coalesced) ----
    {
        const int gtid = (blockIdx.y*gridDim.x + blockIdx.x)*256 + threadIdx.x; // 0..131071
        const float4 z = make_float4(0.f,0.f,0.f,0.f);
#pragma unroll
        for (int k=0;k<8;++k){
            const int i  = gtid + k*131072;              // i-th even-span float4
            const int ei = ((i>>10)<<11) | (i&1023);     // span(ei)=2*(i>>10): even
            outz[ei] = z;
        }
    }

    float amf = bfv[f], apf = bpv[f], amg = bfv[g], apg = bpv[g];
#pragma unroll
    for (int i=0;i<CD;++i){
        const float cv = c[b*CD + i];
        amf += cv * Wf[f*CD + i];
        apf += cv * Wp[f*CD + i];
        amg += cv * Wf[g*CD + i];
        apg += cv * Wp[g*CD + i];
    }
    const float magf = 1.f/(1.f+__expf(-amf));
    const float magg = 1.f/(1.f+__expf(-amg));
    float sf, cf2, sg, cg2;
    __sincosf(apf, &sf, &cf2);
    __sincosf(apg, &sg, &cg2);
    const float scale = 0.5f / (float)FL;
    const float re = (magf*cf2 + magg*cg2)*scale;
    const float im = (magf*sf  - magg*sg )*scale;
    float2* Hb = H + (size_t)b*FL;
    Hb[pos_of_bin(f)] = make_float2(re,  im);
    Hb[pos_of_bin(g)] = make_float2(re, -im);
    if (f == 0){
        // bin 4096 self-pair: Heff[4096] = Re(H[4096]) / N
        float am = bfv[4096], ap = bpv[4096];
#pragma unroll
        for (int i=0;i<CD;++i){
            const float cv = c[b*CD + i];
            am += cv * Wf[4096*CD + i];
            ap += cv * Wp[4096*CD + i];
        }
        const float mag = 1.f/(1.f+__expf(-am));
        Hb[pos_of_bin(4096)] = make_float2(mag*__cosf(ap)*(2.f*scale), 0.f);
    }
}

// ---------------------------------------------------------------------------
// One WG (256 thr x 32 elements) per (block-pair, batch).
// LDS layout: addr(e) = 36*(e>>5) + (e&31) -- 144B block stride, 16B-aligned,
// so pass E runs on uint4 (ds_read_b128/ds_write_b128). Passes A/B 2-way-bank.
// launch_bounds(256,3): 56 VGPR, no spill (r12-r16 verified).
// ---------------------------------------------------------------------------
__global__ __launch_bounds__(256, 3) void fft_kernel(const float*  __restrict__ x,
                                                     const float2* __restrict__ H,
                                                     float* __restrict__ out){
    extern __shared__ __half2 buf[];     // 9216 * 4B = 36 KiB
    const int t  = threadIdx.x;          // 0..255
    const int pr = blockIdx.x;
    const int b  = blockIdx.y;
    const float* xb = x + (size_t)b*SEQ;
    const int s0 = 2*pr*BS - (FL-1);
    const float TWO_PI = 6.28318530717958647692f;

    vf2 d[32];

    constexpr float CT[16] = { 1.f, 0.980785280403230f, 0.923879532511287f, 0.831469612302545f,
                               0.707106781186548f, 0.555570233019602f, 0.382683432365090f, 0.195090322016128f,
                               0.f,-0.195090322016128f,-0.382683432365090f,-0.555570233019602f,
                              -0.707106781186548f,-0.831469612302545f,-0.923879532511287f,-0.980785280403230f };
    constexpr float ST[16] = { 0.f, 0.195090322016128f, 0.382683432365090f, 0.555570233019602f,
                               0.707106781186548f, 0.831469612302545f, 0.923879532511287f, 0.980785280403230f,
                               1.f, 0.980785280403230f, 0.923879532511287f, 0.831469612302545f,
                               0.707106781186548f, 0.555570233019602f, 0.382683432365090f, 0.195090322016128f };

    const int pa0 = BSTR*(t>>5) + (t&31);   // padded addr of element j=t
    // element j=t+256: +8 blocks -> pa0 + 288; pass-A stride 512 -> +576 per q

    // ---- Pass A: radix-16, stride 512; butterflies j=t and j=t+256 ----
    {
        if (pr == 0){
#pragma unroll
            for (int h=0; h<2; ++h){
                const int j = t + 256*h;
#pragma unroll
                for (int m=0;m<8;++m){
                    const int k  = j + 512*m;
                    const int ua = s0 + k, ub = ua + BS;
                    const float va = (ua >= 0) ? xb[ua] : 0.f;
                    const float vb = (ub >= 0) ? xb[ub] : 0.f;
                    d[16*h + m] = mkv(va, vb);
                }
            }
        } else {
            const float* bp = xb + s0;
#pragma unroll
            for (int h=0; h<2; ++h){
                const int j = t + 256*h;
#pragma unroll
                for (int m=0;m<8;++m){
                    const int k = j + 512*m;
                    d[16*h + m] = mkv(bp[k], bp[k + BS]);
                }
            }
        }
        dft16<false,true,1>(d);
        dft16<false,true,1>(d+16);
        float sn, cs; __sincosf(-TWO_PI * (float)t / 8192.f, &sn, &cs);
        const vf2 w0 = mkv(cs, sn);
        tw_apply(d,    w0);
        tw_apply(d+16, cmul(w0, mkv(0.980785280403230f, -0.195090322016128f))); // * e^{-i pi/16}
#pragma unroll
        for (int q=0;q<16;++q){
            sth(buf, pa0       + 576*q, d[q]);
            sth(buf, pa0 + 288 + 576*q, d[16+q]);
        }
    }
    __syncthreads();

    // ---- Pass B: radix-16, stride 32; groups g=t>>5 and g+8, shared j2 ----
    {
        const int j2 = t & 31;
        const int a0 = 576*(t>>5) + j2;    // group g
        const int a1 = a0 + 4608;          // group g+8 (576*8)
#pragma unroll
        for (int m=0;m<16;++m){
            d[m]    = ldh(buf, a0 + BSTR*m);
            d[16+m] = ldh(buf, a1 + BSTR*m);
        }
        dft16<false,false,1>(d);
        dft16<false,false,1>(d+16);
        float sn, cs; __sincosf(-TWO_PI * (float)j2 / 512.f, &sn, &cs);
        tw_apply2(d, mkv(cs, sn));
#pragma unroll
        for (int q=0;q<16;++q){
            sth(buf, a0 + BSTR*q, d[q]);
            sth(buf, a1 + BSTR*q, d[16+q]);
        }
    }
    __syncthreads();

    // ---- Pass E: contiguous 32-block t: DFT32 x Heff x IDFT32 (b128 LDS) ----
    {
        const uint4* __restrict__ srcv = reinterpret_cast<const uint4*>(buf + BSTR*t);
#pragma unroll
        for (int k=0;k<8;++k){
            const uint4 v = srcv[k];
            d[4*k+0] = h2f(v.x); d[4*k+1] = h2f(v.y);
            d[4*k+2] = h2f(v.z); d[4*k+3] = h2f(v.w);
        }
        dft16<false,false,2>(d);       // even elems -> E[k] at d[2k]
        dft16<false,false,2>(d+1);     // odd  elems -> O[k] at d[2k+1]
        const float2* Hb = H + (size_t)b*FL + (t<<5);
#pragma unroll
        for (int w=0;w<16;++w){
            const vf2 Ow = mri(d[2*w+1], CT[w], -ST[w]);   // W32^w * O[w]
            const vf2 Ew = d[2*w];
            vf2 Xlo = Ew + Ow;                             // bin w
            vf2 Xhi = Ew - Ow;                             // bin w+16
            const float2 h0 = Hb[w], h1 = Hb[w+16];
            Xlo = cmul(Xlo, mkv(h0.x, h0.y));
            Xhi = cmul(Xhi, mkv(h1.x, h1.y));
            d[2*w]   = Xlo + Xhi;                          // A_w
            d[2*w+1] = mri(Xlo - Xhi, CT[w], ST[w]);       // B_w = (Xlo-Xhi)*conj(W32^w)
        }
        dft16<true,false,2>(d);        // y[2i]   at d[2i]
        dft16<true,false,2>(d+1);      // y[2i+1] at d[2i+1]
        uint4* __restrict__ dstv = reinterpret_cast<uint4*>(buf + BSTR*t);
#pragma unroll
        for (int k=0;k<8;++k){
            uint4 v;
            v.x = f2h(d[4*k+0]); v.y = f2h(d[4*k+1]);
            v.z = f2h(d[4*k+2]); v.w = f2h(d[4*k+3]);
            dstv[k] = v;
        }
    }
    __syncthreads();

    // ---- Pass B': inverse radix-16, stride 32 (positive-angle twiddles) ----
    {
        const int j2 = t & 31;
        const int a0 = 576*(t>>5) + j2;
        const int a1 = a0 + 4608;
#pragma unroll
        for (int q=0;q<16;++q){
            d[q]    = ldh(buf, a0 + BSTR*q);
            d[16+q] = ldh(buf, a1 + BSTR*q);
        }
        float sn, cs; __sincosf(TWO_PI * (float)j2 / 512.f, &sn, &cs);
        tw_apply2(d, mkv(cs, sn));
        dft16<true,false,1>(d);
        dft16<true,false,1>(d+16);
#pragma unroll
        for (int m=0;m<16;++m){
            sth(buf, a0 + BSTR*m, d[m]);
            sth(buf, a1 + BSTR*m, d[16+m]);
        }
    }
    __syncthreads();

    // ---- Pass A': inverse radix-16, stride 512; direct overlap-add ----
    {
#pragma unroll
        for (int q=0;q<16;++q){
            d[q]    = ldh(buf, pa0       + 576*q);
            d[16+q] = ldh(buf, pa0 + 288 + 576*q);
        }
        float sn, cs; __sincosf(TWO_PI * (float)t / 8192.f, &sn, &cs);
        const vf2 w0 = mkv(cs, sn);
        tw_apply(d,    w0);
        tw_apply(d+16, cmul(w0, mkv(0.980785280403230f, 0.195090322016128f))); // * e^{+i pi/16}
        dft16<true,false,1>(d);
        dft16<true,false,1>(d+16);
        // d[16h+m] = y[time (t+256h) + 512m]; Re -> block a, Im -> block b.
        float* ob = out + (size_t)b*SEQ;
        const int pa = 2*pr*BS;
        const bool last = (pr == NPAIR-1);
#pragma unroll
        for (int h=0; h<2; ++h){
            const int j = t + 256*h;
#pragma unroll
            for (int mm=0;mm<8;++mm){
                const int klo = j + 512*mm;                      // 0..4095
                const vf2 ylo = d[16*h + mm];
                const vf2 yhi = d[16*h + mm + 8];
                atomicAdd(&ob[pa+klo], ylo.x);                   // even span (2 writers)
                ob[pa+BS+klo] = yhi.x + ylo.y;                   // odd span (sole writer)
                if (!last) atomicAdd(&ob[pa+2*BS+klo], yhi.y);   // even span (2 writers)
            }
        }
    }
}

// ---------------------------------------------------------------------------
extern "C" void kernel_launch(void* const* d_in, const int* in_sizes, int n_in,
                              void* d_out, int out_size, void* d_ws, size_t ws_size,
                              hipStream_t stream) {
    const float* x   = (const float*)d_in[0];
    const float* c   = (const float*)d_in[1];
    const float* Wf  = (const float*)d_in[2];
    const float* bfv = (const float*)d_in[3];
    const float* Wp  = (const float*)d_in[4];
    const float* bpv = (const float*)d_in[5];

    float*  out = (float*)d_out;
    float2* H   = (float2*)d_ws;                      // BATCH*FL*8B = 2 MiB

    // h_kernel also zeroes the even output spans (odd spans are plain-stored).
    h_kernel<<<dim3(FL/2/256, BATCH), 256, 0, stream>>>(c, Wf, bfv, Wp, bpv, H,
                                                        (float4*)d_out);
    fft_kernel<<<dim3(NPAIR, BATCH), 256, LDSN*sizeof(__half2), stream>>>(x, H, out);
}